// Round 6
// baseline (336.836 us; speedup 1.0000x reference)
//
#include <hip/hip_runtime.h>
#include <hip/hip_bf16.h>

#define T_TOK 8192
#define DMODEL 1024
#define HDIM 684
#define HPAD 704
#define NEXP 8

typedef short  bf16x8  __attribute__((ext_vector_type(8)));
typedef float  f32x4   __attribute__((ext_vector_type(4)));

__device__ inline unsigned short f2bu(float f) {
    __hip_bfloat16 h = __float2bfloat16(f);   // RNE
    return *reinterpret_cast<unsigned short*>(&h);
}

typedef const __attribute__((address_space(1))) unsigned int* gas_p;
typedef __attribute__((address_space(3))) unsigned int* las_p;
__device__ inline void ld_lds16(const unsigned short* g, unsigned short* l) {
    __builtin_amdgcn_global_load_lds((gas_p)g, (las_p)l, 16, 0, 0);
}

// ---------------- workspace layout (bytes) ----------------
// 0        pair_count[8]@0, offsets[8]@32, cursor[8]@64
// 256      blk_psum f32[2048*8]
// 65792    blk_t1   i32[2048*8]
// 131328   blk_pc   i32[2048*8]
// 196864   topk_idx i32[16384]
// 262400   topk_p   f32[16384]
// 327936   pair_token i32[16384]
// 393472   pair_prob  f32[16384]
// 459264   xb  bf16[8192*1024]
// 17236480 w1b bf16[8*684*1024]
// 28443136 w3b bf16[8*684*1024]
// 39649792 w2b bf16[8*1024*704]  (K padded+zeroed)
// 51184128 h   bf16[16384*704]   (cols 684..703 zeroed by ffn1)
// 74252800 pos i32[16384]
// 74318336 pairs_out f32[16384*1024]   -> end 141427200
#define POS_OFF    74252800ull
#define PAIRS_OFF  74318336ull
#define WS_NEED   141427200ull

// ---------------- conversions (fused: w1, w3, w2-pad in one launch) ----------------
__global__ __launch_bounds__(256) void cvt_all(
    const float* __restrict__ w1, const float* __restrict__ w3, const float* __restrict__ w2,
    unsigned short* __restrict__ w1b, unsigned short* __restrict__ w3b,
    unsigned short* __restrict__ w2b, int n4, int n2)
{
    int i = blockIdx.x * 256 + threadIdx.x;
    if (i < 2 * n4) {
        const float* src; unsigned short* dst; int j;
        if (i < n4) { src = w1; dst = w1b; j = i; }
        else        { src = w3; dst = w3b; j = i - n4; }
        float4 v = ((const float4*)src)[j];
        ((ushort4*)dst)[j] = make_ushort4(f2bu(v.x), f2bu(v.y), f2bu(v.z), f2bu(v.w));
        return;
    }
    int j = i - 2 * n4;
    if (j >= n2) return;
    int row = j / 176;
    int col = (j - row * 176) * 4;
    ushort4 o = make_ushort4(0, 0, 0, 0);
    if (col < HDIM) {
        float4 v = *(const float4*)(w2 + (size_t)row * HDIM + col);
        o = make_ushort4(f2bu(v.x), f2bu(v.y), f2bu(v.z), f2bu(v.w));
    }
    *(ushort4*)(w2b + (size_t)row * HPAD + col) = o;
}

// ---------------- 1. router (+ fused x->bf16), float4 loads ----------------
__global__ __launch_bounds__(256) void moe_router(
    const float* __restrict__ x, const float* __restrict__ rw,
    unsigned short* __restrict__ xb,
    float* __restrict__ blk_psum, int* __restrict__ blk_t1, int* __restrict__ blk_pc,
    int* __restrict__ topk_idx, float* __restrict__ topk_p)
{
    __shared__ float sp[4][NEXP];
    __shared__ int   si1[4], si2[4];

    int lane = threadIdx.x & 63;
    int w    = threadIdx.x >> 6;
    int t    = blockIdx.x * 4 + w;
    const float4* xr4 = (const float4*)(x + (size_t)t * DMODEL);
    ushort4* xbr4 = (ushort4*)(xb + (size_t)t * DMODEL);

    float acc[NEXP];
#pragma unroll
    for (int e = 0; e < NEXP; ++e) acc[e] = 0.f;
#pragma unroll
    for (int j = 0; j < DMODEL / 256; ++j) {
        float4 xv = xr4[j * 64 + lane];
        xbr4[j * 64 + lane] = make_ushort4(f2bu(xv.x), f2bu(xv.y), f2bu(xv.z), f2bu(xv.w));
#pragma unroll
        for (int e = 0; e < NEXP; ++e) {
            float4 rv = ((const float4*)(rw + (size_t)e * DMODEL))[j * 64 + lane];
            acc[e] += xv.x * rv.x + xv.y * rv.y + xv.z * rv.z + xv.w * rv.w;
        }
    }
#pragma unroll
    for (int off = 32; off > 0; off >>= 1) {
#pragma unroll
        for (int e = 0; e < NEXP; ++e)
            acc[e] += __shfl_xor(acc[e], off, 64);
    }
    if (lane == 0) {
        float m = acc[0];
#pragma unroll
        for (int e = 1; e < NEXP; ++e) m = fmaxf(m, acc[e]);
        float p[NEXP]; float s = 0.f;
#pragma unroll
        for (int e = 0; e < NEXP; ++e) { p[e] = expf(acc[e] - m); s += p[e]; }
        float inv = 1.f / s;
#pragma unroll
        for (int e = 0; e < NEXP; ++e) p[e] *= inv;
        int i1 = 0;
#pragma unroll
        for (int e = 1; e < NEXP; ++e) if (p[e] > p[i1]) i1 = e;
        int i2 = (i1 == 0) ? 1 : 0;
#pragma unroll
        for (int e = 0; e < NEXP; ++e) if (e != i1 && p[e] > p[i2]) i2 = e;

        topk_idx[t * 2 + 0] = i1;  topk_idx[t * 2 + 1] = i2;
        topk_p[t * 2 + 0] = p[i1]; topk_p[t * 2 + 1] = p[i2];
#pragma unroll
        for (int e = 0; e < NEXP; ++e) sp[w][e] = p[e];
        si1[w] = i1; si2[w] = i2;
    }
    __syncthreads();
    if (threadIdx.x < NEXP) {
        int e = threadIdx.x;
        float ps = sp[0][e] + sp[1][e] + sp[2][e] + sp[3][e];
        int t1 = (si1[0] == e) + (si1[1] == e) + (si1[2] == e) + (si1[3] == e);
        int pc = t1 + (si2[0] == e) + (si2[1] == e) + (si2[2] == e) + (si2[3] == e);
        blk_psum[blockIdx.x * NEXP + e] = ps;
        blk_t1[blockIdx.x * NEXP + e]  = t1;
        blk_pc[blockIdx.x * NEXP + e]  = pc;
    }
}

// ---------------- 2. scan ----------------
__global__ __launch_bounds__(256) void moe_scan(
    const float* __restrict__ blk_psum, const int* __restrict__ blk_t1,
    const int* __restrict__ blk_pc,
    int* pair_count, int* offsets, int* cursor, float* aux_out)
{
    __shared__ float wp[4][NEXP];
    __shared__ int   wt[4][NEXP], wc[4][NEXP];
    __shared__ float tp[NEXP];
    __shared__ int   tt1[NEXP], tpc[NEXP];

    int tid = threadIdx.x;
    int lane = tid & 63, w = tid >> 6;
    float lp[NEXP]; int lt[NEXP], lc[NEXP];
#pragma unroll
    for (int e = 0; e < NEXP; ++e) { lp[e] = 0.f; lt[e] = 0; lc[e] = 0; }
    for (int b = tid; b < 2048; b += 256)
#pragma unroll
        for (int e = 0; e < NEXP; ++e) {
            lp[e] += blk_psum[b * NEXP + e];
            lt[e] += blk_t1[b * NEXP + e];
            lc[e] += blk_pc[b * NEXP + e];
        }
#pragma unroll
    for (int off = 32; off > 0; off >>= 1) {
#pragma unroll
        for (int e = 0; e < NEXP; ++e) {
            lp[e] += __shfl_xor(lp[e], off, 64);
            lt[e] += __shfl_xor(lt[e], off, 64);
            lc[e] += __shfl_xor(lc[e], off, 64);
        }
    }
    if (lane == 0) {
#pragma unroll
        for (int e = 0; e < NEXP; ++e) { wp[w][e] = lp[e]; wt[w][e] = lt[e]; wc[w][e] = lc[e]; }
    }
    __syncthreads();
    if (tid < NEXP) {
        int e = tid;
        float s = wp[0][e] + wp[1][e] + wp[2][e] + wp[3][e];
        int t1 = wt[0][e] + wt[1][e] + wt[2][e] + wt[3][e];
        int pc = wc[0][e] + wc[1][e] + wc[2][e] + wc[3][e];
        tp[e] = s; tt1[e] = t1; tpc[e] = pc;
        pair_count[e] = pc;
    }
    __syncthreads();
    if (tid == 0) {
        int run = 0;
        for (int e = 0; e < NEXP; ++e) { offsets[e] = run; cursor[e] = run; run += tpc[e]; }
        float s = 0.f;
        for (int e = 0; e < NEXP; ++e)
            s += ((float)tt1[e] / (float)T_TOK) * (tp[e] / (float)T_TOK);
        aux_out[0] = 0.01f * s * (float)NEXP;
    }
}

// ---------------- 3. scatter (records each token-slot's pair position) ----------------
__global__ __launch_bounds__(256) void moe_scatter(
    const int* __restrict__ topk_idx, const float* __restrict__ topk_p,
    int* cursor, int* __restrict__ pair_token, float* __restrict__ pair_prob,
    int* __restrict__ pos)
{
    __shared__ int lcnt[NEXP], gbase[NEXP];
    int tid = threadIdx.x;
    if (tid < NEXP) lcnt[tid] = 0;
    __syncthreads();
    int t = blockIdx.x * 256 + tid;
    int e0 = topk_idx[t * 2 + 0], e1 = topk_idx[t * 2 + 1];
    int p0 = atomicAdd(&lcnt[e0], 1);
    int p1 = atomicAdd(&lcnt[e1], 1);
    __syncthreads();
    if (tid < NEXP) gbase[tid] = atomicAdd(&cursor[tid], lcnt[tid]);
    __syncthreads();
    int q0 = gbase[e0] + p0, q1 = gbase[e1] + p1;
    pair_token[q0] = t; pair_prob[q0] = topk_p[t * 2 + 0];
    pair_token[q1] = t; pair_prob[q1] = topk_p[t * 2 + 1];
    pos[t * 2 + 0] = q0; pos[t * 2 + 1] = q1;
}

// ===================== R6: 8-phase-style pipelined GEMMs =====================
// m201 skeleton, derived waits. Phase = K-half of 32. Per array: ring of 4
// half-slots (128 rows x 32 k = 8 KB). Stage runs 3 phases AHEAD (3 glds per
// phase); per-phase vmcnt(3) certifies the NEXT phase's slot and this phase's
// closing barrier publishes it (wait-before-barrier). vmcnt never drains to 0
// until the final 2 phases. Phase body:
//   vmcnt(3) -> ds_read 8xb128 (this phase's frags, slot certified last phase)
//   -> glds 3 (slot p+3; overwrites slot read at p-1, safe: its reads were
//      reg-landed before p-1's MFMAs, ordered by bar2(p-1))
//   -> barrier -> setprio(1) -> 16 MFMA -> setprio(0) -> barrier
// Staging map: thread tid -> row r=tid>>2, phys granule tid&3, source granule
// (tid&3)^((tid>>3)&3); glds dest = base + tid*8 (lane-linear). Read side
// unchanged: sz8 = ((lane>>4)^((fr>>1)&3))*8, valid for 16-aligned row bases.

// ---------------- 4. MFMA GEMM1: h = silu(Xg w1^T) * (Xg w3^T) ----------------
// grid (6, 64, 8); 512 thr = 8 waves (2M x 4N); tile 128x128, wave-tile 64m x 32n
// per phase per wave: 4 A-frags + 2 B1 + 2 B3 reads, 16 MFMA. LDS 96 KB.
__global__ __launch_bounds__(512, 2) void moe_ffn1(
    const unsigned short* __restrict__ xb, const unsigned short* __restrict__ w1b,
    const unsigned short* __restrict__ w3b,
    const int* __restrict__ pair_count, const int* __restrict__ offsets,
    const int* __restrict__ pair_token,
    unsigned short* __restrict__ h)
{
    int e   = blockIdx.z;
    int cnt = pair_count[e];
    int m0  = blockIdx.y * 128;
    if (m0 >= cnt) return;
    int base = offsets[e];
    int n0   = blockIdx.x * 128;

    __shared__ unsigned short aT [4 * 4096];
    __shared__ unsigned short b1T[4 * 4096];
    __shared__ unsigned short b3T[4 * 4096];

    int tid  = threadIdx.x;
    int lane = tid & 63, wave = tid >> 6;
    int wm = wave >> 2, wn = wave & 3;       // wave-tile 64(m) x 32(n)

    int r   = tid >> 2;                      // staged row 0..127
    int ksg = (tid & 3) ^ ((tid >> 3) & 3);  // source granule (swizzled)
    int ar = m0 + r; if (ar >= cnt) ar = cnt - 1;
    const unsigned short* ap = xb + (size_t)pair_token[base + ar] * DMODEL + ksg * 8;
    int br = n0 + r; if (br > HDIM - 1) br = HDIM - 1;
    const unsigned short* b1p = w1b + ((size_t)e * HDIM + br) * DMODEL + ksg * 8;
    const unsigned short* b3p = w3b + ((size_t)e * HDIM + br) * DMODEL + ksg * 8;
    unsigned short* da  = aT  + tid * 8;
    unsigned short* db1 = b1T + tid * 8;
    unsigned short* db3 = b3T + tid * 8;

#define STG1(slot, kof) do { \
    ld_lds16(ap  + (kof), da  + (slot) * 4096); \
    ld_lds16(b1p + (kof), db1 + (slot) * 4096); \
    ld_lds16(b3p + (kof), db3 + (slot) * 4096); } while (0)

    f32x4 acc1[4][2], acc3[4][2];
#pragma unroll
    for (int i = 0; i < 4; ++i)
#pragma unroll
        for (int j = 0; j < 2; ++j) { acc1[i][j] = (f32x4)(0.f); acc3[i][j] = (f32x4)(0.f); }

    int fr  = lane & 15;
    int sz8 = ((lane >> 4) ^ ((fr >> 1) & 3)) * 8;

    // prologue: slots 0,1,2 staged; certify slot 0, publish
    STG1(0, 0); STG1(1, 32); STG1(2, 64);
    asm volatile("s_waitcnt vmcnt(6)" ::: "memory");
    __builtin_amdgcn_s_barrier();
    asm volatile("" ::: "memory");

    const int P = DMODEL / 32;   // 32 phases
    for (int p = 0; p < P; ++p) {
        int slot = p & 3;
        if (p + 2 < P) asm volatile("s_waitcnt vmcnt(3)" ::: "memory");  // certify slot p+1
        else           asm volatile("s_waitcnt vmcnt(0)" ::: "memory");

        const unsigned short* cA  = aT  + slot * 4096;
        const unsigned short* cB1 = b1T + slot * 4096;
        const unsigned short* cB3 = b3T + slot * 4096;

        bf16x8 aF[4], b1F[2], b3F[2];
#pragma unroll
        for (int i = 0; i < 4; ++i)
            aF[i] = *(const bf16x8*)&cA[(wm * 64 + i * 16 + fr) * 32 + sz8];
#pragma unroll
        for (int j = 0; j < 2; ++j) {
            b1F[j] = *(const bf16x8*)&cB1[(wn * 32 + j * 16 + fr) * 32 + sz8];
            b3F[j] = *(const bf16x8*)&cB3[(wn * 32 + j * 16 + fr) * 32 + sz8];
        }
        if (p + 3 < P) STG1((p + 3) & 3, (p + 3) * 32);

        __builtin_amdgcn_s_barrier();
        asm volatile("" ::: "memory");
        __builtin_amdgcn_s_setprio(1);
#pragma unroll
        for (int j = 0; j < 2; ++j)
#pragma unroll
            for (int i = 0; i < 4; ++i) {
                acc1[i][j] = __builtin_amdgcn_mfma_f32_16x16x32_bf16(aF[i], b1F[j], acc1[i][j], 0, 0, 0);
                acc3[i][j] = __builtin_amdgcn_mfma_f32_16x16x32_bf16(aF[i], b3F[j], acc3[i][j], 0, 0, 0);
            }
        __builtin_amdgcn_s_setprio(0);
        __builtin_amdgcn_s_barrier();
        asm volatile("" ::: "memory");
    }
#undef STG1

    int cbase = n0 + wn * 32 + fr;
    int rbase = m0 + wm * 64 + (lane >> 4) * 4;
#pragma unroll
    for (int i = 0; i < 4; ++i) {
#pragma unroll
        for (int rr = 0; rr < 4; ++rr) {
            int gr = rbase + i * 16 + rr;
            if (gr >= cnt) continue;
            unsigned short* hrow = h + (size_t)(base + gr) * HPAD;
#pragma unroll
            for (int j = 0; j < 2; ++j) {
                int col = cbase + j * 16;
                if (col >= HPAD) continue;
                float v1 = acc1[i][j][rr];
                float hv = (col < HDIM) ? (v1 / (1.f + expf(-v1))) * acc3[i][j][rr] : 0.f;
                hrow[col] = f2bu(hv);
            }
        }
    }
}

// ---------------- 5. MFMA GEMM2: pairs_out[q] = p_q * (h[q] w2^T) ----------------
// grid (4, 64, 8); 512 thr = 8 waves (2M x 4N); tile 128x256, wave-tile 64x64, K=704
// per phase per wave: 4 A-frags + 4 B reads, 16 MFMA. LDS 96 KB (A 32K + B 64K).
__global__ __launch_bounds__(512, 2) void moe_ffn2(
    const unsigned short* __restrict__ h, const unsigned short* __restrict__ w2b,
    const int* __restrict__ pair_count, const int* __restrict__ offsets,
    const int* __restrict__ pair_token, const float* __restrict__ pair_prob,
    float* __restrict__ pairs_out, float* __restrict__ out, int use_atomic)
{
    int e   = blockIdx.z;
    int cnt = pair_count[e];
    int m0  = blockIdx.y * 128;
    if (m0 >= cnt) return;
    int base = offsets[e];
    int n0   = blockIdx.x * 256;

    __shared__ unsigned short aT[4 * 4096];   // 128 x 32 per slot
    __shared__ unsigned short bT[4 * 8192];   // 256 x 32 per slot

    int tid  = threadIdx.x;
    int lane = tid & 63, wave = tid >> 6;
    int wm = wave >> 2, wn = wave & 3;        // wave-tile 64(m) x 64(n)

    int r   = tid >> 2;
    int ksg = (tid & 3) ^ ((tid >> 3) & 3);
    int ar = m0 + r; if (ar >= cnt) ar = cnt - 1;
    const unsigned short* ap  = h + (size_t)(base + ar) * HPAD + ksg * 8;
    const unsigned short* bp0 = w2b + ((size_t)e * DMODEL + n0 + r)       * HPAD + ksg * 8;
    const unsigned short* bp1 = w2b + ((size_t)e * DMODEL + n0 + r + 128) * HPAD + ksg * 8;
    unsigned short* da = aT + tid * 8;
    unsigned short* db = bT + tid * 8;

#define STG2(slot, kof) do { \
    ld_lds16(ap  + (kof), da + (slot) * 4096); \
    ld_lds16(bp0 + (kof), db + (slot) * 8192); \
    ld_lds16(bp1 + (kof), db + (slot) * 8192 + 4096); } while (0)

    f32x4 acc[4][4];
#pragma unroll
    for (int i = 0; i < 4; ++i)
#pragma unroll
        for (int j = 0; j < 4; ++j) acc[i][j] = (f32x4)(0.f);

    int fr  = lane & 15;
    int sz8 = ((lane >> 4) ^ ((fr >> 1) & 3)) * 8;

    STG2(0, 0); STG2(1, 32); STG2(2, 64);
    asm volatile("s_waitcnt vmcnt(6)" ::: "memory");
    __builtin_amdgcn_s_barrier();
    asm volatile("" ::: "memory");

    const int P = HPAD / 32;   // 22 phases
    for (int p = 0; p < P; ++p) {
        int slot = p & 3;
        if (p + 2 < P) asm volatile("s_waitcnt vmcnt(3)" ::: "memory");
        else           asm volatile("s_waitcnt vmcnt(0)" ::: "memory");

        const unsigned short* cA = aT + slot * 4096;
        const unsigned short* cB = bT + slot * 8192;

        bf16x8 aF[4], bF[4];
#pragma unroll
        for (int i = 0; i < 4; ++i)
            aF[i] = *(const bf16x8*)&cA[(wm * 64 + i * 16 + fr) * 32 + sz8];
#pragma unroll
        for (int j = 0; j < 4; ++j)
            bF[j] = *(const bf16x8*)&cB[(wn * 64 + j * 16 + fr) * 32 + sz8];
        if (p + 3 < P) STG2((p + 3) & 3, (p + 3) * 32);

        __builtin_amdgcn_s_barrier();
        asm volatile("" ::: "memory");
        __builtin_amdgcn_s_setprio(1);
#pragma unroll
        for (int j = 0; j < 4; ++j)
#pragma unroll
            for (int i = 0; i < 4; ++i)
                acc[i][j] = __builtin_amdgcn_mfma_f32_16x16x32_bf16(aF[i], bF[j], acc[i][j], 0, 0, 0);
        __builtin_amdgcn_s_setprio(0);
        __builtin_amdgcn_s_barrier();
        asm volatile("" ::: "memory");
    }
#undef STG2

    int cbase = n0 + wn * 64 + fr;
    int rbase = m0 + wm * 64 + (lane >> 4) * 4;
#pragma unroll
    for (int i = 0; i < 4; ++i) {
#pragma unroll
        for (int rr = 0; rr < 4; ++rr) {
            int gr = rbase + i * 16 + rr;
            if (gr >= cnt) continue;
            int gp = base + gr;
            float pw = pair_prob[gp];
            if (!use_atomic) {
                float* prow = pairs_out + (size_t)gp * DMODEL;
#pragma unroll
                for (int j = 0; j < 4; ++j)
                    prow[cbase + j * 16] = pw * acc[i][j][rr];
            } else {
                float* orow = out + (size_t)pair_token[gp] * DMODEL;
#pragma unroll
                for (int j = 0; j < 4; ++j)
                    atomicAdd(&orow[cbase + j * 16], pw * acc[i][j][rr]);
            }
        }
    }
}

// ---------------- 6. combine: out[t] = pairs_out[q0] + pairs_out[q1] ----------------
__global__ __launch_bounds__(256) void moe_combine(
    const float* __restrict__ pairs_out, const int* __restrict__ pos,
    float* __restrict__ out)
{
    int t = blockIdx.x;
    int c = threadIdx.x;
    int q0 = pos[t * 2 + 0], q1 = pos[t * 2 + 1];
    float4 a = ((const float4*)(pairs_out + (size_t)q0 * DMODEL))[c];
    float4 b = ((const float4*)(pairs_out + (size_t)q1 * DMODEL))[c];
    float4 o;
    o.x = a.x + b.x; o.y = a.y + b.y; o.z = a.z + b.z; o.w = a.w + b.w;
    ((float4*)(out + (size_t)t * DMODEL))[c] = o;
}

// ---------------- launch ----------------
extern "C" void kernel_launch(void* const* d_in, const int* in_sizes, int n_in,
                              void* d_out, int out_size, void* d_ws, size_t ws_size,
                              hipStream_t stream)
{
    const float* x  = (const float*)d_in[0];
    const float* rw = (const float*)d_in[1];
    const float* w1 = (const float*)d_in[2];
    const float* w2 = (const float*)d_in[3];
    const float* w3 = (const float*)d_in[4];
    float* out = (float*)d_out;

    char* ws = (char*)d_ws;
    int*   pair_count = (int*)(ws + 0);
    int*   offsets    = (int*)(ws + 32);
    int*   cursor     = (int*)(ws + 64);
    float* blk_psum   = (float*)(ws + 256);
    int*   blk_t1     = (int*)(ws + 65792);
    int*   blk_pc     = (int*)(ws + 131328);
    int*   topk_idx   = (int*)(ws + 196864);
    float* topk_p     = (float*)(ws + 262400);
    int*   pair_token = (int*)(ws + 327936);
    float* pair_prob  = (float*)(ws + 393472);
    unsigned short* xb  = (unsigned short*)(ws + 459264);
    unsigned short* w1b = (unsigned short*)(ws + 17236480);
    unsigned short* w3b = (unsigned short*)(ws + 28443136);
    unsigned short* w2b = (unsigned short*)(ws + 39649792);
    unsigned short* hbuf= (unsigned short*)(ws + 51184128);
    int*   pos        = (int*)(ws + POS_OFF);
    float* pairs_out  = (float*)(ws + PAIRS_OFF);

    int two_pass = (ws_size >= WS_NEED) ? 1 : 0;
    if (!two_pass)
        hipMemsetAsync(d_out, 0, (size_t)out_size * sizeof(float), stream);

    int n4 = NEXP * HDIM * DMODEL / 4;
    int n2 = NEXP * DMODEL * (HPAD / 4);
    cvt_all<<<(2 * n4 + n2 + 255) / 256, 256, 0, stream>>>(w1, w3, w2, w1b, w3b, w2b, n4, n2);

    moe_router <<<T_TOK / 4, 256, 0, stream>>>(x, rw, xb, blk_psum, blk_t1, blk_pc, topk_idx, topk_p);
    moe_scan   <<<1, 256, 0, stream>>>(blk_psum, blk_t1, blk_pc, pair_count, offsets, cursor,
                                       out + (size_t)T_TOK * DMODEL);
    moe_scatter<<<T_TOK / 256, 256, 0, stream>>>(topk_idx, topk_p, cursor, pair_token, pair_prob, pos);

    moe_ffn1<<<dim3(6, 64, 8), 512, 0, stream>>>(xb, w1b, w3b, pair_count, offsets, pair_token, hbuf);
    moe_ffn2<<<dim3(4, 64, 8), 512, 0, stream>>>(hbuf, w2b, pair_count, offsets, pair_token, pair_prob,
                                                 pairs_out, out, two_pass ? 0 : 1);
    if (two_pass)
        moe_combine<<<T_TOK, 256, 0, stream>>>(pairs_out, pos, out);
}

// Round 7
// 284.609 us; speedup vs baseline: 1.1835x; 1.1835x over previous
//
#include <hip/hip_runtime.h>
#include <hip/hip_bf16.h>

#define T_TOK 8192
#define DMODEL 1024
#define HDIM 684
#define HPAD 704
#define NEXP 8

typedef short  bf16x8  __attribute__((ext_vector_type(8)));
typedef float  f32x4   __attribute__((ext_vector_type(4)));

__device__ inline unsigned short f2bu(float f) {
    __hip_bfloat16 h = __float2bfloat16(f);   // RNE
    return *reinterpret_cast<unsigned short*>(&h);
}

typedef const __attribute__((address_space(1))) unsigned int* gas_p;
typedef __attribute__((address_space(3))) unsigned int* las_p;
__device__ inline void ld_lds16(const unsigned short* g, unsigned short* l) {
    __builtin_amdgcn_global_load_lds((gas_p)g, (las_p)l, 16, 0, 0);
}

// ---------------- workspace layout (bytes) ----------------
// 0        pair_count[8]@0, offsets[8]@32, cursor[8]@64
// 256      blk_psum f32[2048*8]
// 65792    blk_t1   i32[2048*8]
// 131328   blk_pc   i32[2048*8]
// 196864   topk_idx i32[16384]
// 262400   topk_p   f32[16384]
// 327936   pair_token i32[16384]
// 393472   pair_prob  f32[16384]
// 459264   xb  bf16[8192*1024]
// 17236480 w1b bf16[8*684*1024]
// 28443136 w3b bf16[8*684*1024]
// 39649792 w2b bf16[8*1024*704]  (K padded+zeroed)
// 51184128 h   bf16[16384*704]   (cols 684..703 zeroed by ffn1)
// 74252800 pos i32[16384]
// 74318336 pairs_out f32[16384*1024]   -> end 141427200
#define POS_OFF    74252800ull
#define PAIRS_OFF  74318336ull
#define WS_NEED   141427200ull

#define NB_CVT   16576   // ceil((2*n4+n2)/256); n4=1400832, n2=1441792
#define NB_ROUT  2048    // T_TOK/4

// ---------------- 0+1. fused conversions + router ----------------
// blocks [0, NB_CVT): weight conversions (w1,w3 cast; w2 cast+pad)
// blocks [NB_CVT, NB_CVT+NB_ROUT): router (+ x->bf16), 4 tokens/block
__global__ __launch_bounds__(256) void cvt_router(
    const float* __restrict__ w1, const float* __restrict__ w3, const float* __restrict__ w2,
    unsigned short* __restrict__ w1b, unsigned short* __restrict__ w3b,
    unsigned short* __restrict__ w2b,
    const float* __restrict__ x, const float* __restrict__ rw,
    unsigned short* __restrict__ xb,
    float* __restrict__ blk_psum, int* __restrict__ blk_t1, int* __restrict__ blk_pc,
    int* __restrict__ topk_idx, float* __restrict__ topk_p)
{
    const int n4 = NEXP * HDIM * DMODEL / 4;
    const int n2 = NEXP * DMODEL * (HPAD / 4);

    if (blockIdx.x < NB_CVT) {
        int i = blockIdx.x * 256 + threadIdx.x;
        if (i < 2 * n4) {
            const float* src; unsigned short* dst; int j;
            if (i < n4) { src = w1; dst = w1b; j = i; }
            else        { src = w3; dst = w3b; j = i - n4; }
            float4 v = ((const float4*)src)[j];
            ((ushort4*)dst)[j] = make_ushort4(f2bu(v.x), f2bu(v.y), f2bu(v.z), f2bu(v.w));
            return;
        }
        int j = i - 2 * n4;
        if (j >= n2) return;
        int row = j / 176;
        int col = (j - row * 176) * 4;
        ushort4 o = make_ushort4(0, 0, 0, 0);
        if (col < HDIM) {
            float4 v = *(const float4*)(w2 + (size_t)row * HDIM + col);
            o = make_ushort4(f2bu(v.x), f2bu(v.y), f2bu(v.z), f2bu(v.w));
        }
        *(ushort4*)(w2b + (size_t)row * HPAD + col) = o;
        return;
    }

    // ---- router role ----
    __shared__ float sp[4][NEXP];
    __shared__ int   si1[4], si2[4];

    int bid  = blockIdx.x - NB_CVT;
    int lane = threadIdx.x & 63;
    int w    = threadIdx.x >> 6;
    int t    = bid * 4 + w;
    const float4* xr4 = (const float4*)(x + (size_t)t * DMODEL);
    ushort4* xbr4 = (ushort4*)(xb + (size_t)t * DMODEL);

    float acc[NEXP];
#pragma unroll
    for (int e = 0; e < NEXP; ++e) acc[e] = 0.f;
#pragma unroll
    for (int j = 0; j < DMODEL / 256; ++j) {
        float4 xv = xr4[j * 64 + lane];
        xbr4[j * 64 + lane] = make_ushort4(f2bu(xv.x), f2bu(xv.y), f2bu(xv.z), f2bu(xv.w));
#pragma unroll
        for (int e = 0; e < NEXP; ++e) {
            float4 rv = ((const float4*)(rw + (size_t)e * DMODEL))[j * 64 + lane];
            acc[e] += xv.x * rv.x + xv.y * rv.y + xv.z * rv.z + xv.w * rv.w;
        }
    }
#pragma unroll
    for (int off = 32; off > 0; off >>= 1) {
#pragma unroll
        for (int e = 0; e < NEXP; ++e)
            acc[e] += __shfl_xor(acc[e], off, 64);
    }
    if (lane == 0) {
        float m = acc[0];
#pragma unroll
        for (int e = 1; e < NEXP; ++e) m = fmaxf(m, acc[e]);
        float p[NEXP]; float s = 0.f;
#pragma unroll
        for (int e = 0; e < NEXP; ++e) { p[e] = expf(acc[e] - m); s += p[e]; }
        float inv = 1.f / s;
#pragma unroll
        for (int e = 0; e < NEXP; ++e) p[e] *= inv;
        int i1 = 0;
#pragma unroll
        for (int e = 1; e < NEXP; ++e) if (p[e] > p[i1]) i1 = e;
        int i2 = (i1 == 0) ? 1 : 0;
#pragma unroll
        for (int e = 0; e < NEXP; ++e) if (e != i1 && p[e] > p[i2]) i2 = e;

        topk_idx[t * 2 + 0] = i1;  topk_idx[t * 2 + 1] = i2;
        topk_p[t * 2 + 0] = p[i1]; topk_p[t * 2 + 1] = p[i2];
#pragma unroll
        for (int e = 0; e < NEXP; ++e) sp[w][e] = p[e];
        si1[w] = i1; si2[w] = i2;
    }
    __syncthreads();
    if (threadIdx.x < NEXP) {
        int e = threadIdx.x;
        float ps = sp[0][e] + sp[1][e] + sp[2][e] + sp[3][e];
        int t1 = (si1[0] == e) + (si1[1] == e) + (si1[2] == e) + (si1[3] == e);
        int pc = t1 + (si2[0] == e) + (si2[1] == e) + (si2[2] == e) + (si2[3] == e);
        blk_psum[bid * NEXP + e] = ps;
        blk_t1[bid * NEXP + e]  = t1;
        blk_pc[bid * NEXP + e]  = pc;
    }
}

// ---------------- 2. scan ----------------
__global__ __launch_bounds__(256) void moe_scan(
    const float* __restrict__ blk_psum, const int* __restrict__ blk_t1,
    const int* __restrict__ blk_pc,
    int* pair_count, int* offsets, int* cursor, float* aux_out)
{
    __shared__ float wp[4][NEXP];
    __shared__ int   wt[4][NEXP], wc[4][NEXP];
    __shared__ float tp[NEXP];
    __shared__ int   tt1[NEXP], tpc[NEXP];

    int tid = threadIdx.x;
    int lane = tid & 63, w = tid >> 6;
    float lp[NEXP]; int lt[NEXP], lc[NEXP];
#pragma unroll
    for (int e = 0; e < NEXP; ++e) { lp[e] = 0.f; lt[e] = 0; lc[e] = 0; }
    for (int b = tid; b < 2048; b += 256)
#pragma unroll
        for (int e = 0; e < NEXP; ++e) {
            lp[e] += blk_psum[b * NEXP + e];
            lt[e] += blk_t1[b * NEXP + e];
            lc[e] += blk_pc[b * NEXP + e];
        }
#pragma unroll
    for (int off = 32; off > 0; off >>= 1) {
#pragma unroll
        for (int e = 0; e < NEXP; ++e) {
            lp[e] += __shfl_xor(lp[e], off, 64);
            lt[e] += __shfl_xor(lt[e], off, 64);
            lc[e] += __shfl_xor(lc[e], off, 64);
        }
    }
    if (lane == 0) {
#pragma unroll
        for (int e = 0; e < NEXP; ++e) { wp[w][e] = lp[e]; wt[w][e] = lt[e]; wc[w][e] = lc[e]; }
    }
    __syncthreads();
    if (tid < NEXP) {
        int e = tid;
        float s = wp[0][e] + wp[1][e] + wp[2][e] + wp[3][e];
        int t1 = wt[0][e] + wt[1][e] + wt[2][e] + wt[3][e];
        int pc = wc[0][e] + wc[1][e] + wc[2][e] + wc[3][e];
        tp[e] = s; tt1[e] = t1; tpc[e] = pc;
        pair_count[e] = pc;
    }
    __syncthreads();
    if (tid == 0) {
        int run = 0;
        for (int e = 0; e < NEXP; ++e) { offsets[e] = run; cursor[e] = run; run += tpc[e]; }
        float s = 0.f;
        for (int e = 0; e < NEXP; ++e)
            s += ((float)tt1[e] / (float)T_TOK) * (tp[e] / (float)T_TOK);
        aux_out[0] = 0.01f * s * (float)NEXP;
    }
}

// ---------------- 3. scatter (records each token-slot's pair position) ----------------
__global__ __launch_bounds__(256) void moe_scatter(
    const int* __restrict__ topk_idx, const float* __restrict__ topk_p,
    int* cursor, int* __restrict__ pair_token, float* __restrict__ pair_prob,
    int* __restrict__ pos)
{
    __shared__ int lcnt[NEXP], gbase[NEXP];
    int tid = threadIdx.x;
    if (tid < NEXP) lcnt[tid] = 0;
    __syncthreads();
    int t = blockIdx.x * 256 + tid;
    int e0 = topk_idx[t * 2 + 0], e1 = topk_idx[t * 2 + 1];
    int p0 = atomicAdd(&lcnt[e0], 1);
    int p1 = atomicAdd(&lcnt[e1], 1);
    __syncthreads();
    if (tid < NEXP) gbase[tid] = atomicAdd(&cursor[tid], lcnt[tid]);
    __syncthreads();
    int q0 = gbase[e0] + p0, q1 = gbase[e1] + p1;
    pair_token[q0] = t; pair_prob[q0] = topk_p[t * 2 + 0];
    pair_token[q1] = t; pair_prob[q1] = topk_p[t * 2 + 1];
    pos[t * 2 + 0] = q0; pos[t * 2 + 1] = q1;
}

// ========== R7 GEMMs: exact R4 schedule (proven best), grid permuted ==========
// blockIdx.x = EXPERT (fastest-varying) -> consecutive block IDs round-robin
// XCDs -> expert e's blocks concentrate on XCD e%8. Per-XCD L2 working set:
// ffn1: 2.8 MB weights + ~4 MB expert tokens (was 38 MB all-experts); ffn2:
// 1.4 MB w2 + 2.9 MB h-slab -> L2-resident. Attacks measured FETCH=131 MB vs
// 38 MB unique (L2 thrash -> L3/HBM latency on every staged tile).
// Schedule per R4: 3-buffer, wait vmcnt(L) BEFORE barrier (L=loads/tile),
// stage tile it+2 AFTER compute. Granule swizzle verified conflict-free.

// ---------------- 4. MFMA GEMM1: h = silu(Xg w1^T) * (Xg w3^T) ----------------
// grid (8, 64, 6); 512 thr = 8 waves; tile 128x128, wave-tile 32x64, BK=32
__global__ __launch_bounds__(512, 4) void moe_ffn1(
    const unsigned short* __restrict__ xb, const unsigned short* __restrict__ w1b,
    const unsigned short* __restrict__ w3b,
    const int* __restrict__ pair_count, const int* __restrict__ offsets,
    const int* __restrict__ pair_token,
    unsigned short* __restrict__ h)
{
    int e   = blockIdx.x;                 // expert fastest -> XCD affinity
    int cnt = pair_count[e];
    int m0  = blockIdx.y * 128;
    if (m0 >= cnt) return;
    int base = offsets[e];
    int n0   = blockIdx.z * 128;

    __shared__ unsigned short aT[3 * 4096];
    __shared__ unsigned short b1T[3 * 4096];
    __shared__ unsigned short b3T[3 * 4096];

    int tid  = threadIdx.x;
    int lane = tid & 63, wave = tid >> 6;
    int wm = wave >> 1, wn = wave & 1;

    int srow = lane >> 2;
    int ksg  = (lane & 3) ^ ((lane >> 3) & 3);
    int arow = m0 + wave * 16 + srow; if (arow >= cnt) arow = cnt - 1;
    const unsigned short* ap  = xb + (size_t)pair_token[base + arow] * DMODEL + ksg * 8;
    int brow = n0 + wave * 16 + srow; if (brow > HDIM - 1) brow = HDIM - 1;
    const unsigned short* b1p = w1b + ((size_t)e * HDIM + brow) * DMODEL + ksg * 8;
    const unsigned short* b3p = w3b + ((size_t)e * HDIM + brow) * DMODEL + ksg * 8;
    unsigned short* sA  = aT  + wave * 512;
    unsigned short* sB1 = b1T + wave * 512;
    unsigned short* sB3 = b3T + wave * 512;

    f32x4 acc1[2][4], acc3[2][4];
#pragma unroll
    for (int i = 0; i < 2; ++i)
#pragma unroll
        for (int j = 0; j < 4; ++j) { acc1[i][j] = (f32x4)(0.f); acc3[i][j] = (f32x4)(0.f); }

    int fr  = lane & 15;
    int sz8 = ((lane >> 4) ^ ((fr >> 1) & 3)) * 8;

    // prologue: tiles 0 and 1
    ld_lds16(ap,        sA);
    ld_lds16(b1p,       sB1);
    ld_lds16(b3p,       sB3);
    ld_lds16(ap  + 32,  sA  + 4096);
    ld_lds16(b1p + 32,  sB1 + 4096);
    ld_lds16(b3p + 32,  sB3 + 4096);

    const int NIT = DMODEL / 32;   // 32
    for (int it = 0; it < NIT; ++it) {
        int buf = it % 3;
        if (it + 1 < NIT) asm volatile("s_waitcnt vmcnt(3)" ::: "memory");
        else              asm volatile("s_waitcnt vmcnt(0)" ::: "memory");
        __builtin_amdgcn_s_barrier();
        asm volatile("" ::: "memory");

        const unsigned short* cA  = aT  + buf * 4096;
        const unsigned short* cB1 = b1T + buf * 4096;
        const unsigned short* cB3 = b3T + buf * 4096;

        bf16x8 aF[2];
#pragma unroll
        for (int i = 0; i < 2; ++i)
            aF[i] = *(const bf16x8*)&cA[(wm * 32 + i * 16 + fr) * 32 + sz8];
        __builtin_amdgcn_s_setprio(1);
#pragma unroll
        for (int j = 0; j < 4; ++j) {
            int row = (wn * 64 + j * 16 + fr) * 32 + sz8;
            bf16x8 b1F = *(const bf16x8*)&cB1[row];
            bf16x8 b3F = *(const bf16x8*)&cB3[row];
#pragma unroll
            for (int i = 0; i < 2; ++i) {
                acc1[i][j] = __builtin_amdgcn_mfma_f32_16x16x32_bf16(aF[i], b1F, acc1[i][j], 0, 0, 0);
                acc3[i][j] = __builtin_amdgcn_mfma_f32_16x16x32_bf16(aF[i], b3F, acc3[i][j], 0, 0, 0);
            }
        }
        __builtin_amdgcn_s_setprio(0);

        if (it + 2 < NIT) {
            int nb = (it + 2) % 3;
            int nk = (it + 2) * 32;
            ld_lds16(ap  + nk, aT  + nb * 4096 + wave * 512);
            ld_lds16(b1p + nk, b1T + nb * 4096 + wave * 512);
            ld_lds16(b3p + nk, b3T + nb * 4096 + wave * 512);
        }
    }

    int cbase = n0 + wn * 64 + fr;
    int rbase = m0 + wm * 32 + (lane >> 4) * 4;
#pragma unroll
    for (int i = 0; i < 2; ++i) {
#pragma unroll
        for (int r = 0; r < 4; ++r) {
            int gr = rbase + i * 16 + r;
            if (gr >= cnt) continue;
            unsigned short* hrow = h + (size_t)(base + gr) * HPAD;
#pragma unroll
            for (int j = 0; j < 4; ++j) {
                int col = cbase + j * 16;
                if (col >= HPAD) continue;
                float v1 = acc1[i][j][r];
                float hv = (col < HDIM) ? (v1 / (1.f + expf(-v1))) * acc3[i][j][r] : 0.f;
                hrow[col] = f2bu(hv);
            }
        }
    }
}

// ---------------- 5. MFMA GEMM2: pairs_out[q] = p_q * (h[q] w2^T) ----------------
// grid (8, 64, 8); 512 thr = 8 waves; tile 128x128, wave-tile 32x64, K=704
__global__ __launch_bounds__(512, 4) void moe_ffn2(
    const unsigned short* __restrict__ h, const unsigned short* __restrict__ w2b,
    const int* __restrict__ pair_count, const int* __restrict__ offsets,
    const int* __restrict__ pair_token, const float* __restrict__ pair_prob,
    float* __restrict__ pairs_out, float* __restrict__ out, int use_atomic)
{
    int e   = blockIdx.x;                 // expert fastest -> XCD affinity
    int cnt = pair_count[e];
    int m0  = blockIdx.y * 128;
    if (m0 >= cnt) return;
    int base = offsets[e];
    int n0   = blockIdx.z * 128;

    __shared__ unsigned short aT[3 * 4096];
    __shared__ unsigned short bT[3 * 4096];

    int tid  = threadIdx.x;
    int lane = tid & 63, wave = tid >> 6;
    int wm = wave >> 1, wn = wave & 1;

    int srow = lane >> 2;
    int ksg  = (lane & 3) ^ ((lane >> 3) & 3);
    int arow = m0 + wave * 16 + srow; if (arow >= cnt) arow = cnt - 1;
    const unsigned short* ap = h + (size_t)(base + arow) * HPAD + ksg * 8;
    const unsigned short* bp = w2b + ((size_t)e * DMODEL + n0 + wave * 16 + srow) * HPAD + ksg * 8;
    unsigned short* sA = aT + wave * 512;
    unsigned short* sB = bT + wave * 512;

    f32x4 acc[2][4];
#pragma unroll
    for (int i = 0; i < 2; ++i)
#pragma unroll
        for (int j = 0; j < 4; ++j) acc[i][j] = (f32x4)(0.f);

    int fr  = lane & 15;
    int sz8 = ((lane >> 4) ^ ((fr >> 1) & 3)) * 8;

    // prologue: tiles 0 and 1
    ld_lds16(ap,      sA);
    ld_lds16(bp,      sB);
    ld_lds16(ap + 32, sA + 4096);
    ld_lds16(bp + 32, sB + 4096);

    const int NIT = HPAD / 32;   // 22
    for (int it = 0; it < NIT; ++it) {
        int buf = it % 3;
        if (it + 1 < NIT) asm volatile("s_waitcnt vmcnt(2)" ::: "memory");
        else              asm volatile("s_waitcnt vmcnt(0)" ::: "memory");
        __builtin_amdgcn_s_barrier();
        asm volatile("" ::: "memory");

        const unsigned short* cA = aT + buf * 4096;
        const unsigned short* cB = bT + buf * 4096;

        bf16x8 aF[2];
#pragma unroll
        for (int i = 0; i < 2; ++i)
            aF[i] = *(const bf16x8*)&cA[(wm * 32 + i * 16 + fr) * 32 + sz8];
        __builtin_amdgcn_s_setprio(1);
#pragma unroll
        for (int j = 0; j < 4; ++j) {
            bf16x8 bF = *(const bf16x8*)&cB[(wn * 64 + j * 16 + fr) * 32 + sz8];
#pragma unroll
            for (int i = 0; i < 2; ++i)
                acc[i][j] = __builtin_amdgcn_mfma_f32_16x16x32_bf16(aF[i], bF, acc[i][j], 0, 0, 0);
        }
        __builtin_amdgcn_s_setprio(0);

        if (it + 2 < NIT) {
            int nb = (it + 2) % 3;
            int nk = (it + 2) * 32;
            ld_lds16(ap + nk, aT + nb * 4096 + wave * 512);
            ld_lds16(bp + nk, bT + nb * 4096 + wave * 512);
        }
    }

    int cbase = n0 + wn * 64 + fr;
    int rbase = m0 + wm * 32 + (lane >> 4) * 4;
#pragma unroll
    for (int i = 0; i < 2; ++i) {
#pragma unroll
        for (int r = 0; r < 4; ++r) {
            int gr = rbase + i * 16 + r;
            if (gr >= cnt) continue;
            int gp = base + gr;
            float pw = pair_prob[gp];
            if (!use_atomic) {
                float* prow = pairs_out + (size_t)gp * DMODEL;
#pragma unroll
                for (int j = 0; j < 4; ++j)
                    prow[cbase + j * 16] = pw * acc[i][j][r];
            } else {
                float* orow = out + (size_t)pair_token[gp] * DMODEL;
#pragma unroll
                for (int j = 0; j < 4; ++j)
                    atomicAdd(&orow[cbase + j * 16], pw * acc[i][j][r]);
            }
        }
    }
}

// ---------------- 6. combine: out[t] = pairs_out[q0] + pairs_out[q1] ----------------
__global__ __launch_bounds__(256) void moe_combine(
    const float* __restrict__ pairs_out, const int* __restrict__ pos,
    float* __restrict__ out)
{
    int t = blockIdx.x;
    int c = threadIdx.x;
    int q0 = pos[t * 2 + 0], q1 = pos[t * 2 + 1];
    float4 a = ((const float4*)(pairs_out + (size_t)q0 * DMODEL))[c];
    float4 b = ((const float4*)(pairs_out + (size_t)q1 * DMODEL))[c];
    float4 o;
    o.x = a.x + b.x; o.y = a.y + b.y; o.z = a.z + b.z; o.w = a.w + b.w;
    ((float4*)(out + (size_t)t * DMODEL))[c] = o;
}

// ---------------- launch ----------------
extern "C" void kernel_launch(void* const* d_in, const int* in_sizes, int n_in,
                              void* d_out, int out_size, void* d_ws, size_t ws_size,
                              hipStream_t stream)
{
    const float* x  = (const float*)d_in[0];
    const float* rw = (const float*)d_in[1];
    const float* w1 = (const float*)d_in[2];
    const float* w2 = (const float*)d_in[3];
    const float* w3 = (const float*)d_in[4];
    float* out = (float*)d_out;

    char* ws = (char*)d_ws;
    int*   pair_count = (int*)(ws + 0);
    int*   offsets    = (int*)(ws + 32);
    int*   cursor     = (int*)(ws + 64);
    float* blk_psum   = (float*)(ws + 256);
    int*   blk_t1     = (int*)(ws + 65792);
    int*   blk_pc     = (int*)(ws + 131328);
    int*   topk_idx   = (int*)(ws + 196864);
    float* topk_p     = (float*)(ws + 262400);
    int*   pair_token = (int*)(ws + 327936);
    float* pair_prob  = (float*)(ws + 393472);
    unsigned short* xb  = (unsigned short*)(ws + 459264);
    unsigned short* w1b = (unsigned short*)(ws + 17236480);
    unsigned short* w3b = (unsigned short*)(ws + 28443136);
    unsigned short* w2b = (unsigned short*)(ws + 39649792);
    unsigned short* hbuf= (unsigned short*)(ws + 51184128);
    int*   pos        = (int*)(ws + POS_OFF);
    float* pairs_out  = (float*)(ws + PAIRS_OFF);

    int two_pass = (ws_size >= WS_NEED) ? 1 : 0;
    if (!two_pass)
        hipMemsetAsync(d_out, 0, (size_t)out_size * sizeof(float), stream);

    cvt_router<<<NB_CVT + NB_ROUT, 256, 0, stream>>>(
        w1, w3, w2, w1b, w3b, w2b,
        x, rw, xb, blk_psum, blk_t1, blk_pc, topk_idx, topk_p);

    moe_scan   <<<1, 256, 0, stream>>>(blk_psum, blk_t1, blk_pc, pair_count, offsets, cursor,
                                       out + (size_t)T_TOK * DMODEL);
    moe_scatter<<<T_TOK / 256, 256, 0, stream>>>(topk_idx, topk_p, cursor, pair_token, pair_prob, pos);

    moe_ffn1<<<dim3(8, 64, 6), 512, 0, stream>>>(xb, w1b, w3b, pair_count, offsets, pair_token, hbuf);
    moe_ffn2<<<dim3(8, 64, 8), 512, 0, stream>>>(hbuf, w2b, pair_count, offsets, pair_token, pair_prob,
                                                 pairs_out, out, two_pass ? 0 : 1);
    if (two_pass)
        moe_combine<<<T_TOK, 256, 0, stream>>>(pairs_out, pos, out);
}